// Round 12
// baseline (78.033 us; speedup 1.0000x reference)
//
#include <hip/hip_runtime.h>
#include <cmath>

namespace {
constexpr int B_ = 2, K_ = 4, D_ = 128, L_ = 4096, N_ = 16, R_ = 8, C_ = 40;
constexpr int CHUNK = 32, NCH = L_ / CHUNK;   // 128 chunks of 32
constexpr int GC = 4, GL = GC * CHUNK;        // 4 chunks/group, 128 l/group
constexpr int NG = NCH / GC;                  // 32 groups
constexpr float LOG2E = 1.44269504f;
}

#if __has_builtin(__builtin_amdgcn_exp2f)
#define FEXP2(x) __builtin_amdgcn_exp2f(x)
#else
#define FEXP2(x) exp2f(x)
#endif

// ===========================================================================
// k1: projections (r7 verbatim). 256 blocks x 640 thr (10 waves); wave w
// computes 4 channels (w0-5 kv: dts+B, w6-9 q: C). X from global (VMEM pipe),
// W from LDS broadcast (2-way, free) - pipe-balanced.
// ===========================================================================
__global__ __launch_bounds__(640, 2) void k1_proj(
    const float* __restrict__ qx, const float* __restrict__ kv,
    const float* __restrict__ xw,
    float* __restrict__ dtsT, float* __restrict__ BT, float* __restrict__ CT)
{
    __shared__ float Wt[D_ * C_];   // [d][c]

    const int tid = threadIdx.x;
    const int w = tid >> 6, lane = tid & 63;
    const int dg = lane >> 5, lq = lane & 31;
    int blk = blockIdx.x;
    const int lt = blk & 31; blk >>= 5;
    const int k = blk & 3; const int b = blk >> 2;
    const int bk = b * K_ + k;

    for (int i = tid; i < C_ * D_; i += 640) {
        const int c = i >> 7, d = i & 127;
        Wt[d * C_ + c] = xw[(k * C_ + c) * D_ + d];
    }
    __syncthreads();

    const float* xsrc = (w >= 6) ? qx : kv;
    const int c0 = w * 4;
    float acc[4][4];
    #pragma unroll
    for (int c = 0; c < 4; ++c)
        #pragma unroll
        for (int j = 0; j < 4; ++j) acc[c][j] = 0.f;

    const float* src = xsrc + ((size_t)bk * D_ + dg * 64) * L_ + lt * 128 + 4 * lq;
    #pragma unroll 8
    for (int dd = 0; dd < 64; ++dd) {
        const float4 x = *(const float4*)(src + (size_t)dd * L_);
        const float4 wv = *(const float4*)&Wt[(dg * 64 + dd) * C_ + c0];
        const float* wp = (const float*)&wv;
        #pragma unroll
        for (int c = 0; c < 4; ++c) {
            acc[c][0] = fmaf(x.x, wp[c], acc[c][0]);
            acc[c][1] = fmaf(x.y, wp[c], acc[c][1]);
            acc[c][2] = fmaf(x.z, wp[c], acc[c][2]);
            acc[c][3] = fmaf(x.w, wp[c], acc[c][3]);
        }
    }

    #pragma unroll
    for (int c = 0; c < 4; ++c)
        #pragma unroll
        for (int j = 0; j < 4; ++j)
            acc[c][j] += __shfl_xor(acc[c][j], 32, 64);

    if (dg == 0) {
        #pragma unroll
        for (int j = 0; j < 4; ++j) {
            const int l = lt * 128 + 4 * lq + j;
            float4 o; o.x = acc[0][j]; o.y = acc[1][j]; o.z = acc[2][j]; o.w = acc[3][j];
            if (w < 2)
                *(float4*)(dtsT + ((size_t)bk * L_ + l) * R_ + w * 4) = o;
            else if (w < 6)
                *(float4*)(BT + ((size_t)bk * L_ + l) * N_ + (w - 2) * 4) = o;
            else
                *(float4*)(CT + ((size_t)bk * L_ + l) * N_ + (w - 6) * 4) = o;
        }
    }
}

// ===========================================================================
// k2v2: pass-1 over a GROUP of 4 chunks, h NOT reset between chunks ->
// within-group exclusive prefixes (hpart, Spre) recorded for free at each
// chunk entry. Group summary (hgend, Sgrp) written at end. Grid 256 (bk,g),
// 128 thr (thread = d).
// ===========================================================================
__global__ __launch_bounds__(128, 1) void k2v2_pass1(
    const float* __restrict__ kv, const float* __restrict__ dtsT,
    const float* __restrict__ BT, const float* __restrict__ alg,
    const float* __restrict__ dtw, const float* __restrict__ dtb,
    float* __restrict__ hpart,  // (B,K,NCH,D,N) h at chunk entry (group-local)
    float* __restrict__ Spre,   // (B,K,NCH,D)   sum-delta at chunk entry
    float* __restrict__ hgend,  // (B,K,NG,D,N)  h at group end
    float* __restrict__ Sgrp)   // (B,K,NG,D)    sum-delta over group
{
    __shared__ float dts_s[GL * R_];   // 4 KB
    __shared__ float B_s[GL * N_];     // 8 KB

    const int tid = threadIdx.x;
    const int d = tid;
    const int g  = blockIdx.x & (NG - 1);
    const int bk = blockIdx.x >> 5;
    const int k = bk & 3;
    const int l0 = g * GL;

    {
        const float4* src = (const float4*)(dtsT + ((size_t)bk * L_ + l0) * R_);
        ((float4*)dts_s)[tid]       = src[tid];
        ((float4*)dts_s)[tid + 128] = src[tid + 128];
        const float4* bsrc = (const float4*)(BT + ((size_t)bk * L_ + l0) * N_);
        #pragma unroll
        for (int f = 0; f < 4; ++f)
            ((float4*)B_s)[tid + f * 128] = bsrc[tid + f * 128];
    }

    float dtwr[R_];
    {
        const float* p = dtw + ((size_t)k * D_ + d) * R_;
        *(float4*)&dtwr[0] = *(const float4*)p;
        *(float4*)&dtwr[4] = *(const float4*)(p + 4);
    }
    const float bias = dtb[k * D_ + d];
    float A2[N_];
    {
        const float* ap = alg + ((size_t)k * D_ + d) * N_;
        #pragma unroll
        for (int j = 0; j < 4; ++j) {
            float4 a = *(const float4*)(ap + 4 * j);
            A2[4*j]   = -__expf(a.x) * LOG2E; A2[4*j+1] = -__expf(a.y) * LOG2E;
            A2[4*j+2] = -__expf(a.z) * LOG2E; A2[4*j+3] = -__expf(a.w) * LOG2E;
        }
    }
    __syncthreads();

    float h[N_];
    #pragma unroll
    for (int n = 0; n < N_; ++n) h[n] = 0.f;
    float sd = 0.f;

    #pragma unroll
    for (int p = 0; p < GC; ++p) {
        const int ch = g * GC + p;
        // record chunk-entry state (group-local exclusive prefix)
        {
            float* hp = hpart + (((size_t)bk * NCH + ch) * D_ + d) * N_;
            #pragma unroll
            for (int j = 0; j < 4; ++j) {
                float4 o; o.x = h[4*j]; o.y = h[4*j+1]; o.z = h[4*j+2]; o.w = h[4*j+3];
                *(float4*)(hp + 4 * j) = o;
            }
            Spre[((size_t)bk * NCH + ch) * D_ + d] = sd;
        }
        // load this chunk's u (contiguous per-thread)
        float uu[CHUNK];
        {
            const float4* up = (const float4*)(kv + ((size_t)bk * D_ + d) * L_ + ch * CHUNK);
            #pragma unroll
            for (int j = 0; j < 8; ++j) {
                const float4 v = up[j];
                uu[4*j] = v.x; uu[4*j+1] = v.y; uu[4*j+2] = v.z; uu[4*j+3] = v.w;
            }
        }
        #pragma unroll
        for (int l = 0; l < CHUNK; ++l) {
            const int ll = p * CHUNK + l;
            float dv[R_];
            *(float4*)&dv[0] = *(const float4*)&dts_s[ll * R_];
            *(float4*)&dv[4] = *(const float4*)&dts_s[ll * R_ + 4];
            float s = bias;
            #pragma unroll
            for (int r = 0; r < R_; ++r) s = fmaf(dv[r], dtwr[r], s);
            const float e = FEXP2(s * LOG2E);
            const float dlt = (s > 15.f) ? s : __logf(1.f + e);
            sd += dlt;
            const float xb = dlt * uu[l];
            #pragma unroll
            for (int gg = 0; gg < 4; ++gg) {
                const float4 bg = *(const float4*)&B_s[ll * N_ + 4 * gg];
                h[4*gg+0] = fmaf(FEXP2(dlt * A2[4*gg+0]), h[4*gg+0], xb * bg.x);
                h[4*gg+1] = fmaf(FEXP2(dlt * A2[4*gg+1]), h[4*gg+1], xb * bg.y);
                h[4*gg+2] = fmaf(FEXP2(dlt * A2[4*gg+2]), h[4*gg+2], xb * bg.z);
                h[4*gg+3] = fmaf(FEXP2(dlt * A2[4*gg+3]), h[4*gg+3], xb * bg.w);
            }
        }
    }

    {
        float* hp = hgend + (((size_t)bk * NG + g) * D_ + d) * N_;
        #pragma unroll
        for (int j = 0; j < 4; ++j) {
            float4 o; o.x = h[4*j]; o.y = h[4*j+1]; o.z = h[4*j+2]; o.w = h[4*j+3];
            *(float4*)(hp + 4 * j) = o;
        }
        Sgrp[((size_t)bk * NG + g) * D_ + d] = sd;
    }
}

// ===========================================================================
// k25b: serial chain over 32 GROUPS (4x shorter, 4x less data than before).
// Thread = (bk,d,n); hgend -> hginit exclusive prefix, fully unrolled.
// ===========================================================================
__global__ __launch_bounds__(64, 2) void k25b_chain(
    const float* __restrict__ alg, const float* __restrict__ Sgrp,
    const float* __restrict__ hgend, float* __restrict__ hginit)
{
    const int tg = blockIdx.x * 64 + threadIdx.x;   // 16384 threads
    const int n = tg & 15;
    const int d = (tg >> 4) & 127;
    const int bk = tg >> 11;
    const int k = bk & 3;

    const float A2 = -__expf(alg[((size_t)k * D_ + d) * N_ + n]) * LOG2E;
    float he[NG], ss[NG];
    #pragma unroll
    for (int j = 0; j < NG; ++j) {
        const size_t si = ((size_t)bk * NG + j) * D_ + d;
        he[j] = hgend[si * N_ + n];
        ss[j] = Sgrp[si];
    }
    float h = 0.f;
    #pragma unroll
    for (int j = 0; j < NG; ++j) {
        const size_t si = ((size_t)bk * NG + j) * D_ + d;
        hginit[si * N_ + n] = h;
        h = fmaf(FEXP2(ss[j] * A2), h, he[j]);
    }
}

// ===========================================================================
// k3: pass-2 (r7 structure). Init: h = exp2(Spre*A2)*hginit(group) + hpart.
// ===========================================================================
__global__ __launch_bounds__(128, 1) void k3_pass2(
    const float* __restrict__ kv, const float* __restrict__ dtsT,
    const float* __restrict__ BT, const float* __restrict__ CT,
    const float* __restrict__ alg, const float* __restrict__ dtw,
    const float* __restrict__ dtb, const float* __restrict__ DsG,
    const float* __restrict__ hpart, const float* __restrict__ Spre,
    const float* __restrict__ hginit, float* __restrict__ out)
{
    constexpr int YS = CHUNK + 1;
    __shared__ float dts_s[CHUNK * R_];
    __shared__ float B_s[CHUNK * N_];
    __shared__ float C_s[CHUNK * N_];
    __shared__ float y_s[D_ * YS];
    const int tid = threadIdx.x;
    const int d = tid;
    const int blk = blockIdx.x;
    const int ch = blk & (NCH - 1);
    const int bk = blk >> 7;
    const int k = bk & 3;

    {
        const float* src = dtsT + ((size_t)bk * L_ + ch * CHUNK) * R_;
        if (tid < 64) *(float4*)&dts_s[4 * tid] = *(const float4*)(src + 4 * tid);
        const float* bsrc = BT + ((size_t)bk * L_ + ch * CHUNK) * N_;
        *(float4*)&B_s[4 * tid] = *(const float4*)(bsrc + 4 * tid);
        const float* csrc = CT + ((size_t)bk * L_ + ch * CHUNK) * N_;
        *(float4*)&C_s[4 * tid] = *(const float4*)(csrc + 4 * tid);
    }
    float uu[CHUNK];
    {
        const float4* up = (const float4*)(kv + ((size_t)bk * D_ + d) * L_ + ch * CHUNK);
        #pragma unroll
        for (int j = 0; j < 8; ++j) {
            const float4 v = up[j];
            uu[4*j] = v.x; uu[4*j+1] = v.y; uu[4*j+2] = v.z; uu[4*j+3] = v.w;
        }
    }
    float dtwr[R_];
    {
        const float* p = dtw + ((size_t)k * D_ + d) * R_;
        *(float4*)&dtwr[0] = *(const float4*)p;
        *(float4*)&dtwr[4] = *(const float4*)(p + 4);
    }
    const float bias = dtb[k * D_ + d];
    const float Dv = DsG[k * D_ + d];
    float A2[N_];
    {
        const float* ap = alg + ((size_t)k * D_ + d) * N_;
        #pragma unroll
        for (int j = 0; j < 4; ++j) {
            float4 a = *(const float4*)(ap + 4 * j);
            A2[4*j]   = -__expf(a.x) * LOG2E; A2[4*j+1] = -__expf(a.y) * LOG2E;
            A2[4*j+2] = -__expf(a.z) * LOG2E; A2[4*j+3] = -__expf(a.w) * LOG2E;
        }
    }
    // init: h = exp2(Spre*A2) * hginit(group) + hpart(chunk)
    float h[N_];
    {
        const float Sp = Spre[((size_t)bk * NCH + ch) * D_ + d];
        const float* hp = hpart + (((size_t)bk * NCH + ch) * D_ + d) * N_;
        const float* hg = hginit + (((size_t)bk * NG + (ch >> 2)) * D_ + d) * N_;
        #pragma unroll
        for (int j = 0; j < 4; ++j) {
            float4 vp = *(const float4*)(hp + 4 * j);
            float4 vg = *(const float4*)(hg + 4 * j);
            h[4*j+0] = fmaf(FEXP2(Sp * A2[4*j+0]), vg.x, vp.x);
            h[4*j+1] = fmaf(FEXP2(Sp * A2[4*j+1]), vg.y, vp.y);
            h[4*j+2] = fmaf(FEXP2(Sp * A2[4*j+2]), vg.z, vp.z);
            h[4*j+3] = fmaf(FEXP2(Sp * A2[4*j+3]), vg.w, vp.w);
        }
    }
    __syncthreads();

    #pragma unroll
    for (int l = 0; l < CHUNK; ++l) {
        float dv[R_];
        *(float4*)&dv[0] = *(const float4*)&dts_s[l * R_];
        *(float4*)&dv[4] = *(const float4*)&dts_s[l * R_ + 4];
        float s = bias;
        #pragma unroll
        for (int r = 0; r < R_; ++r) s = fmaf(dv[r], dtwr[r], s);
        const float e = FEXP2(s * LOG2E);
        const float dlt = (s > 15.f) ? s : __logf(1.f + e);
        const float xb = dlt * uu[l];
        float p0 = 0.f, p1 = 0.f;
        #pragma unroll
        for (int g = 0; g < 4; ++g) {
            const float4 bg = *(const float4*)&B_s[l * N_ + 4 * g];
            const float4 cg4 = *(const float4*)&C_s[l * N_ + 4 * g];
            h[4*g+0] = fmaf(FEXP2(dlt * A2[4*g+0]), h[4*g+0], xb * bg.x);
            p0 = fmaf(h[4*g+0], cg4.x, p0);
            h[4*g+1] = fmaf(FEXP2(dlt * A2[4*g+1]), h[4*g+1], xb * bg.y);
            p1 = fmaf(h[4*g+1], cg4.y, p1);
            h[4*g+2] = fmaf(FEXP2(dlt * A2[4*g+2]), h[4*g+2], xb * bg.z);
            p0 = fmaf(h[4*g+2], cg4.z, p0);
            h[4*g+3] = fmaf(FEXP2(dlt * A2[4*g+3]), h[4*g+3], xb * bg.w);
            p1 = fmaf(h[4*g+3], cg4.w, p1);
        }
        y_s[d * YS + l] = fmaf(uu[l], Dv, p0 + p1);
    }
    __syncthreads();

    #pragma unroll
    for (int p = 0; p < 8; ++p) {
        const int f = tid + p * 128;
        const int row = f >> 3, j4 = (f & 7) * 4;
        const float* yp = &y_s[row * YS + j4];
        float4 o; o.x = yp[0]; o.y = yp[1]; o.z = yp[2]; o.w = yp[3];
        *(float4*)(out + ((size_t)bk * D_ + row) * L_ + ch * CHUNK + j4) = o;
    }
}

extern "C" void kernel_launch(void* const* d_in, const int* in_sizes, int n_in,
                              void* d_out, int out_size, void* d_ws, size_t ws_size,
                              hipStream_t stream)
{
    const float* qx  = (const float*)d_in[0];
    const float* kv  = (const float*)d_in[1];
    const float* xw  = (const float*)d_in[2];
    const float* dtw = (const float*)d_in[3];
    const float* dtb = (const float*)d_in[4];
    const float* alg = (const float*)d_in[5];
    const float* Ds  = (const float*)d_in[6];
    float* out = (float*)d_out;

    const size_t sz_dts  = (size_t)B_ * K_ * L_ * R_;        //   262,144
    const size_t sz_bc   = (size_t)B_ * K_ * L_ * N_;        //   524,288
    const size_t sz_hp   = (size_t)B_ * K_ * NCH * D_ * N_;  // 2,097,152
    const size_t sz_sp   = (size_t)B_ * K_ * NCH * D_;       //   131,072
    const size_t sz_hg   = (size_t)B_ * K_ * NG * D_ * N_;   //   524,288
    const size_t sz_sg   = (size_t)B_ * K_ * NG * D_;        //    32,768
    const size_t need = (sz_dts + 2 * sz_bc + sz_hp + sz_sp + 2 * sz_hg + sz_sg) * sizeof(float);
    if (ws_size < need) return;   // ~18.6 MB

    float* dts    = (float*)d_ws;
    float* BTp    = dts + sz_dts;
    float* CTp    = BTp + sz_bc;
    float* hpart  = CTp + sz_bc;
    float* Spre   = hpart + sz_hp;
    float* hgend  = Spre + sz_sp;
    float* hginit = hgend + sz_hg;
    float* Sgrp   = hginit + sz_hg;

    k1_proj<<<B_ * K_ * 32, 640, 0, stream>>>(qx, kv, xw, dts, BTp, CTp);
    k2v2_pass1<<<B_ * K_ * NG, 128, 0, stream>>>(kv, dts, BTp, alg, dtw, dtb,
                                                 hpart, Spre, hgend, Sgrp);
    k25b_chain<<<256, 64, 0, stream>>>(alg, Sgrp, hgend, hginit);
    k3_pass2<<<B_ * K_ * NCH, 128, 0, stream>>>(kv, dts, BTp, CTp, alg, dtw, dtb,
                                                Ds, hpart, Spre, hginit, out);
}

// Round 13
// 66.619 us; speedup vs baseline: 1.1713x; 1.1713x over previous
//
#include <hip/hip_runtime.h>
#include <cmath>

namespace {
constexpr int B_ = 2, K_ = 4, D_ = 128, L_ = 4096, N_ = 16, R_ = 8, C_ = 40;
constexpr int CHUNK = 32, NCH = L_ / CHUNK;   // 128 chunks of 32
constexpr int SGC = 16, NSG = NCH / SGC;      // 16 chunks/supergroup, 8 sgs
constexpr float LOG2E = 1.44269504f;
}

#if __has_builtin(__builtin_amdgcn_exp2f)
#define FEXP2(x) __builtin_amdgcn_exp2f(x)
#else
#define FEXP2(x) exp2f(x)
#endif

// ===========================================================================
// k1: projections (r7 verbatim). 256 blocks x 640 thr (10 waves); wave w
// computes 4 channels (w0-5 kv: dts+B, w6-9 q: C). X via VMEM, W via LDS
// broadcast - pipe-balanced.
// ===========================================================================
__global__ __launch_bounds__(640, 2) void k1_proj(
    const float* __restrict__ qx, const float* __restrict__ kv,
    const float* __restrict__ xw,
    float* __restrict__ dtsT, float* __restrict__ BT, float* __restrict__ CT)
{
    __shared__ float Wt[D_ * C_];   // [d][c]

    const int tid = threadIdx.x;
    const int w = tid >> 6, lane = tid & 63;
    const int dg = lane >> 5, lq = lane & 31;
    int blk = blockIdx.x;
    const int lt = blk & 31; blk >>= 5;
    const int k = blk & 3; const int b = blk >> 2;
    const int bk = b * K_ + k;

    for (int i = tid; i < C_ * D_; i += 640) {
        const int c = i >> 7, d = i & 127;
        Wt[d * C_ + c] = xw[(k * C_ + c) * D_ + d];
    }
    __syncthreads();

    const float* xsrc = (w >= 6) ? qx : kv;
    const int c0 = w * 4;
    float acc[4][4];
    #pragma unroll
    for (int c = 0; c < 4; ++c)
        #pragma unroll
        for (int j = 0; j < 4; ++j) acc[c][j] = 0.f;

    const float* src = xsrc + ((size_t)bk * D_ + dg * 64) * L_ + lt * 128 + 4 * lq;
    #pragma unroll 8
    for (int dd = 0; dd < 64; ++dd) {
        const float4 x = *(const float4*)(src + (size_t)dd * L_);
        const float4 wv = *(const float4*)&Wt[(dg * 64 + dd) * C_ + c0];
        const float* wp = (const float*)&wv;
        #pragma unroll
        for (int c = 0; c < 4; ++c) {
            acc[c][0] = fmaf(x.x, wp[c], acc[c][0]);
            acc[c][1] = fmaf(x.y, wp[c], acc[c][1]);
            acc[c][2] = fmaf(x.z, wp[c], acc[c][2]);
            acc[c][3] = fmaf(x.w, wp[c], acc[c][3]);
        }
    }

    #pragma unroll
    for (int c = 0; c < 4; ++c)
        #pragma unroll
        for (int j = 0; j < 4; ++j)
            acc[c][j] += __shfl_xor(acc[c][j], 32, 64);

    if (dg == 0) {
        #pragma unroll
        for (int j = 0; j < 4; ++j) {
            const int l = lt * 128 + 4 * lq + j;
            float4 o; o.x = acc[0][j]; o.y = acc[1][j]; o.z = acc[2][j]; o.w = acc[3][j];
            if (w < 2)
                *(float4*)(dtsT + ((size_t)bk * L_ + l) * R_ + w * 4) = o;
            else if (w < 6)
                *(float4*)(BT + ((size_t)bk * L_ + l) * N_ + (w - 2) * 4) = o;
            else
                *(float4*)(CT + ((size_t)bk * L_ + l) * N_ + (w - 6) * 4) = o;
        }
    }
}

// ===========================================================================
// k2: chunk pass 1 (r7 verbatim). Grid 1024 (4 blocks/CU), thread = d,
// u direct from kv (contiguous per-thread).
// ===========================================================================
__global__ __launch_bounds__(128, 1) void k2_pass1(
    const float* __restrict__ kv, const float* __restrict__ dtsT,
    const float* __restrict__ BT, const float* __restrict__ alg,
    const float* __restrict__ dtw, const float* __restrict__ dtb,
    float* __restrict__ hend, float* __restrict__ Ssum)
{
    __shared__ float dts_s[CHUNK * R_];   // 1 KB
    __shared__ float B_s[CHUNK * N_];     // 2 KB

    const int tid = threadIdx.x;
    const int d = tid;
    const int blk = blockIdx.x;
    const int ch = blk & (NCH - 1);
    const int bk = blk >> 7;
    const int k = bk & 3;

    {
        const float* src = dtsT + ((size_t)bk * L_ + ch * CHUNK) * R_;
        if (tid < 64) *(float4*)&dts_s[4 * tid] = *(const float4*)(src + 4 * tid);
        const float* bsrc = BT + ((size_t)bk * L_ + ch * CHUNK) * N_;
        *(float4*)&B_s[4 * tid] = *(const float4*)(bsrc + 4 * tid);
    }

    float uu[CHUNK];
    {
        const float4* up = (const float4*)(kv + ((size_t)bk * D_ + d) * L_ + ch * CHUNK);
        #pragma unroll
        for (int j = 0; j < 8; ++j) {
            const float4 v = up[j];
            uu[4*j] = v.x; uu[4*j+1] = v.y; uu[4*j+2] = v.z; uu[4*j+3] = v.w;
        }
    }

    float dtwr[R_];
    {
        const float* p = dtw + ((size_t)k * D_ + d) * R_;
        *(float4*)&dtwr[0] = *(const float4*)p;
        *(float4*)&dtwr[4] = *(const float4*)(p + 4);
    }
    const float bias = dtb[k * D_ + d];
    float A2[N_];
    {
        const float* ap = alg + ((size_t)k * D_ + d) * N_;
        #pragma unroll
        for (int j = 0; j < 4; ++j) {
            float4 a = *(const float4*)(ap + 4 * j);
            A2[4*j]   = -__expf(a.x) * LOG2E; A2[4*j+1] = -__expf(a.y) * LOG2E;
            A2[4*j+2] = -__expf(a.z) * LOG2E; A2[4*j+3] = -__expf(a.w) * LOG2E;
        }
    }
    __syncthreads();

    float h[N_];
    #pragma unroll
    for (int n = 0; n < N_; ++n) h[n] = 0.f;
    float sd = 0.f;

    #pragma unroll
    for (int l = 0; l < CHUNK; ++l) {
        float dv[R_];
        *(float4*)&dv[0] = *(const float4*)&dts_s[l * R_];
        *(float4*)&dv[4] = *(const float4*)&dts_s[l * R_ + 4];
        float s = bias;
        #pragma unroll
        for (int r = 0; r < R_; ++r) s = fmaf(dv[r], dtwr[r], s);
        const float e = FEXP2(s * LOG2E);
        const float dlt = (s > 15.f) ? s : __logf(1.f + e);
        sd += dlt;
        const float xb = dlt * uu[l];
        #pragma unroll
        for (int g = 0; g < 4; ++g) {
            const float4 bg = *(const float4*)&B_s[l * N_ + 4 * g];
            h[4*g+0] = fmaf(FEXP2(dlt * A2[4*g+0]), h[4*g+0], xb * bg.x);
            h[4*g+1] = fmaf(FEXP2(dlt * A2[4*g+1]), h[4*g+1], xb * bg.y);
            h[4*g+2] = fmaf(FEXP2(dlt * A2[4*g+2]), h[4*g+2], xb * bg.z);
            h[4*g+3] = fmaf(FEXP2(dlt * A2[4*g+3]), h[4*g+3], xb * bg.w);
        }
    }

    float* hp = hend + (((size_t)bk * NCH + ch) * D_ + d) * N_;
    #pragma unroll
    for (int j = 0; j < 4; ++j) {
        float4 o; o.x = h[4*j]; o.y = h[4*j+1]; o.z = h[4*j+2]; o.w = h[4*j+3];
        *(float4*)(hp + 4 * j) = o;
    }
    Ssum[((size_t)bk * NCH + ch) * D_ + d] = sd;
}

// ===========================================================================
// k25a: LOCAL chains, one supergroup (16 chunks) per thread. 131072 threads
// = 2048 waves = 8 waves/CU (8x r7's k25 parallelism). Writes per-chunk
// local exclusive prefixes (hloc, Sloc) + supergroup summary (hsg_end, Ssg).
// ===========================================================================
__global__ __launch_bounds__(64, 4) void k25a_local(
    const float* __restrict__ alg, const float* __restrict__ Ssum,
    const float* __restrict__ hend,
    float* __restrict__ hloc, float* __restrict__ Sloc,
    float* __restrict__ hsg_end, float* __restrict__ Ssg)
{
    const int tg = blockIdx.x * 64 + threadIdx.x;   // 131072 threads
    const int n  = tg & 15;
    const int d  = (tg >> 4) & 127;
    const int sg = (tg >> 11) & (NSG - 1);
    const int bk = tg >> 14;
    const int k  = bk & 3;

    const float A2 = -__expf(alg[((size_t)k * D_ + d) * N_ + n]) * LOG2E;

    float he[SGC], ss[SGC];
    #pragma unroll
    for (int j = 0; j < SGC; ++j) {
        const size_t si = ((size_t)bk * NCH + sg * SGC + j) * D_ + d;
        he[j] = hend[si * N_ + n];
        ss[j] = Ssum[si];
    }
    float h = 0.f, s = 0.f;
    #pragma unroll
    for (int j = 0; j < SGC; ++j) {
        const size_t si = ((size_t)bk * NCH + sg * SGC + j) * D_ + d;
        hloc[si * N_ + n] = h;
        if (n == 0) Sloc[si] = s;
        h = fmaf(FEXP2(ss[j] * A2), h, he[j]);
        s += ss[j];
    }
    const size_t gi = ((size_t)bk * NSG + sg) * D_ + d;
    hsg_end[gi * N_ + n] = h;
    if (n == 0) Ssg[gi] = s;
}

// ===========================================================================
// k25b: supergroup chain (8 steps). 16384 threads. hsg_end -> hsg_init.
// ===========================================================================
__global__ __launch_bounds__(64, 4) void k25b_chain(
    const float* __restrict__ alg, const float* __restrict__ Ssg,
    const float* __restrict__ hsg_end, float* __restrict__ hsg_init)
{
    const int tg = blockIdx.x * 64 + threadIdx.x;   // 16384 threads
    const int n = tg & 15;
    const int d = (tg >> 4) & 127;
    const int bk = tg >> 11;
    const int k = bk & 3;

    const float A2 = -__expf(alg[((size_t)k * D_ + d) * N_ + n]) * LOG2E;
    float he[NSG], ss[NSG];
    #pragma unroll
    for (int j = 0; j < NSG; ++j) {
        const size_t gi = ((size_t)bk * NSG + j) * D_ + d;
        he[j] = hsg_end[gi * N_ + n];
        ss[j] = Ssg[gi];
    }
    float h = 0.f;
    #pragma unroll
    for (int j = 0; j < NSG; ++j) {
        const size_t gi = ((size_t)bk * NSG + j) * D_ + d;
        hsg_init[gi * N_ + n] = h;
        h = fmaf(FEXP2(ss[j] * A2), h, he[j]);
    }
}

// ===========================================================================
// k3: pass-2 (r7 verbatim except init). Init:
// h = hloc[ch] + exp2(Sloc[ch]*A2) * hsg_init[sg],  sg = ch/16.
// ===========================================================================
__global__ __launch_bounds__(128, 1) void k3_pass2(
    const float* __restrict__ kv, const float* __restrict__ dtsT,
    const float* __restrict__ BT, const float* __restrict__ CT,
    const float* __restrict__ alg, const float* __restrict__ dtw,
    const float* __restrict__ dtb, const float* __restrict__ DsG,
    const float* __restrict__ hloc, const float* __restrict__ Sloc,
    const float* __restrict__ hsg_init, float* __restrict__ out)
{
    constexpr int YS = CHUNK + 1;
    __shared__ float dts_s[CHUNK * R_];
    __shared__ float B_s[CHUNK * N_];
    __shared__ float C_s[CHUNK * N_];
    __shared__ float y_s[D_ * YS];
    const int tid = threadIdx.x;
    const int d = tid;
    const int blk = blockIdx.x;
    const int ch = blk & (NCH - 1);
    const int bk = blk >> 7;
    const int k = bk & 3;

    {
        const float* src = dtsT + ((size_t)bk * L_ + ch * CHUNK) * R_;
        if (tid < 64) *(float4*)&dts_s[4 * tid] = *(const float4*)(src + 4 * tid);
        const float* bsrc = BT + ((size_t)bk * L_ + ch * CHUNK) * N_;
        *(float4*)&B_s[4 * tid] = *(const float4*)(bsrc + 4 * tid);
        const float* csrc = CT + ((size_t)bk * L_ + ch * CHUNK) * N_;
        *(float4*)&C_s[4 * tid] = *(const float4*)(csrc + 4 * tid);
    }
    float uu[CHUNK];
    {
        const float4* up = (const float4*)(kv + ((size_t)bk * D_ + d) * L_ + ch * CHUNK);
        #pragma unroll
        for (int j = 0; j < 8; ++j) {
            const float4 v = up[j];
            uu[4*j] = v.x; uu[4*j+1] = v.y; uu[4*j+2] = v.z; uu[4*j+3] = v.w;
        }
    }
    float dtwr[R_];
    {
        const float* p = dtw + ((size_t)k * D_ + d) * R_;
        *(float4*)&dtwr[0] = *(const float4*)p;
        *(float4*)&dtwr[4] = *(const float4*)(p + 4);
    }
    const float bias = dtb[k * D_ + d];
    const float Dv = DsG[k * D_ + d];
    float A2[N_];
    {
        const float* ap = alg + ((size_t)k * D_ + d) * N_;
        #pragma unroll
        for (int j = 0; j < 4; ++j) {
            float4 a = *(const float4*)(ap + 4 * j);
            A2[4*j]   = -__expf(a.x) * LOG2E; A2[4*j+1] = -__expf(a.y) * LOG2E;
            A2[4*j+2] = -__expf(a.z) * LOG2E; A2[4*j+3] = -__expf(a.w) * LOG2E;
        }
    }
    // init: h = hloc + exp2(Sloc*A2) * hsg_init
    float h[N_];
    {
        const float Sp = Sloc[((size_t)bk * NCH + ch) * D_ + d];
        const float* hp = hloc + (((size_t)bk * NCH + ch) * D_ + d) * N_;
        const float* hg = hsg_init + (((size_t)bk * NSG + (ch >> 4)) * D_ + d) * N_;
        #pragma unroll
        for (int j = 0; j < 4; ++j) {
            float4 vp = *(const float4*)(hp + 4 * j);
            float4 vg = *(const float4*)(hg + 4 * j);
            h[4*j+0] = fmaf(FEXP2(Sp * A2[4*j+0]), vg.x, vp.x);
            h[4*j+1] = fmaf(FEXP2(Sp * A2[4*j+1]), vg.y, vp.y);
            h[4*j+2] = fmaf(FEXP2(Sp * A2[4*j+2]), vg.z, vp.z);
            h[4*j+3] = fmaf(FEXP2(Sp * A2[4*j+3]), vg.w, vp.w);
        }
    }
    __syncthreads();

    #pragma unroll
    for (int l = 0; l < CHUNK; ++l) {
        float dv[R_];
        *(float4*)&dv[0] = *(const float4*)&dts_s[l * R_];
        *(float4*)&dv[4] = *(const float4*)&dts_s[l * R_ + 4];
        float s = bias;
        #pragma unroll
        for (int r = 0; r < R_; ++r) s = fmaf(dv[r], dtwr[r], s);
        const float e = FEXP2(s * LOG2E);
        const float dlt = (s > 15.f) ? s : __logf(1.f + e);
        const float xb = dlt * uu[l];
        float p0 = 0.f, p1 = 0.f;
        #pragma unroll
        for (int g = 0; g < 4; ++g) {
            const float4 bg = *(const float4*)&B_s[l * N_ + 4 * g];
            const float4 cg4 = *(const float4*)&C_s[l * N_ + 4 * g];
            h[4*g+0] = fmaf(FEXP2(dlt * A2[4*g+0]), h[4*g+0], xb * bg.x);
            p0 = fmaf(h[4*g+0], cg4.x, p0);
            h[4*g+1] = fmaf(FEXP2(dlt * A2[4*g+1]), h[4*g+1], xb * bg.y);
            p1 = fmaf(h[4*g+1], cg4.y, p1);
            h[4*g+2] = fmaf(FEXP2(dlt * A2[4*g+2]), h[4*g+2], xb * bg.z);
            p0 = fmaf(h[4*g+2], cg4.z, p0);
            h[4*g+3] = fmaf(FEXP2(dlt * A2[4*g+3]), h[4*g+3], xb * bg.w);
            p1 = fmaf(h[4*g+3], cg4.w, p1);
        }
        y_s[d * YS + l] = fmaf(uu[l], Dv, p0 + p1);
    }
    __syncthreads();

    #pragma unroll
    for (int p = 0; p < 8; ++p) {
        const int f = tid + p * 128;
        const int row = f >> 3, j4 = (f & 7) * 4;
        const float* yp = &y_s[row * YS + j4];
        float4 o; o.x = yp[0]; o.y = yp[1]; o.z = yp[2]; o.w = yp[3];
        *(float4*)(out + ((size_t)bk * D_ + row) * L_ + ch * CHUNK + j4) = o;
    }
}

extern "C" void kernel_launch(void* const* d_in, const int* in_sizes, int n_in,
                              void* d_out, int out_size, void* d_ws, size_t ws_size,
                              hipStream_t stream)
{
    const float* qx  = (const float*)d_in[0];
    const float* kv  = (const float*)d_in[1];
    const float* xw  = (const float*)d_in[2];
    const float* dtw = (const float*)d_in[3];
    const float* dtb = (const float*)d_in[4];
    const float* alg = (const float*)d_in[5];
    const float* Ds  = (const float*)d_in[6];
    float* out = (float*)d_out;

    const size_t sz_dts = (size_t)B_ * K_ * L_ * R_;         //   262,144
    const size_t sz_bc  = (size_t)B_ * K_ * L_ * N_;         //   524,288
    const size_t sz_h   = (size_t)B_ * K_ * NCH * D_ * N_;   // 2,097,152
    const size_t sz_ss  = (size_t)B_ * K_ * NCH * D_;        //   131,072
    const size_t sz_hg  = (size_t)B_ * K_ * NSG * D_ * N_;   //   131,072
    const size_t sz_sg  = (size_t)B_ * K_ * NSG * D_;        //     8,192
    const size_t need = (sz_dts + 2 * sz_bc + 2 * sz_h + 2 * sz_ss
                         + 2 * sz_hg + sz_sg) * sizeof(float);
    if (ws_size < need) return;   // ~23 MB

    float* dts     = (float*)d_ws;
    float* BTp     = dts + sz_dts;
    float* CTp     = BTp + sz_bc;
    float* hend    = CTp + sz_bc;
    float* hloc    = hend + sz_h;
    float* Ssm     = hloc + sz_h;
    float* SlocB   = Ssm + sz_ss;
    float* hsgEnd  = SlocB + sz_ss;
    float* hsgInit = hsgEnd + sz_hg;
    float* SsgB    = hsgInit + sz_hg;

    k1_proj<<<B_ * K_ * 32, 640, 0, stream>>>(qx, kv, xw, dts, BTp, CTp);
    k2_pass1<<<B_ * K_ * NCH, 128, 0, stream>>>(kv, dts, BTp, alg, dtw, dtb, hend, Ssm);
    k25a_local<<<B_ * K_ * NSG * D_ * N_ / 64, 64, 0, stream>>>(alg, Ssm, hend,
                                                                hloc, SlocB, hsgEnd, SsgB);
    k25b_chain<<<256, 64, 0, stream>>>(alg, SsgB, hsgEnd, hsgInit);
    k3_pass2<<<B_ * K_ * NCH, 128, 0, stream>>>(kv, dts, BTp, CTp, alg, dtw, dtb,
                                                Ds, hloc, SlocB, hsgInit, out);
}